// Round 5
// baseline (467.968 us; speedup 1.0000x reference)
//
#include <hip/hip_runtime.h>
#include <math.h>

#define Bsz 8
#define Hc 32
#define Lc 32768
#define Nst 32
#define CDc 128
#define CHK 256
#define NCH (Lc / CHK) /* 128 */

// ---- workspace layout (float offsets) ----  total 10564672 floats = 42.3 MB
// (y_ssm intermediate lives in d_out, NOT here, to keep ws small)
#define OFF_U 0            /* u[B][H][L]          8388608 (reused for yg after k_glu) */
#define OFF_SIN 8388608    /* Sin[B*H][NCH][N][2] 2097152 */
#define OFF_K 10485760     /* K_local[H][CHK]     8192    */
#define OFF_LO 10493952    /* lo[H][N][16][2]     32768   */
#define OFF_HI 10526720    /* hi[H][N][17][2]     34816   */
#define OFF_CD 10561536    /* Cd[H][N][2]         2048    */
#define OFF_SUMP 10563584  /* [32][8]             256     */
#define OFF_SQP 10563840   /* [32][8]             256     */
#define OFF_MEAN 10564096  /* [32]                32      */
#define OFF_INV 10564128   /* [32]                32      */
#define OFF_GB 10564160    /* gb[B][64]           512     */

__device__ __forceinline__ float gelu_f(float v) {
    const float c = 0.7978845608028654f;
    return 0.5f * v * (1.0f + tanhf(c * (v + 0.044715f * v * v * v)));
}

// ---------------------------------------------------------------------------
// Kernel B: per-(h,n) discretization + power tables + short local kernel K
// ---------------------------------------------------------------------------
__global__ void k_tables(const float* __restrict__ logdt, const float* __restrict__ Are,
                         const float* __restrict__ Aim, const float* __restrict__ Cre,
                         const float* __restrict__ Cim, float* __restrict__ ws) {
    int h = blockIdx.x;
    int t = threadIdx.x;
    __shared__ float are_s[32], aim_s[32], cdr_s[32], cdi_s[32];
    if (t < 32) {
        int n = t;
        float dt = expf(logdt[h]);
        float ar = Are[h * 32 + n], ai = Aim[h * 32 + n];
        float dar = dt * ar, dai = dt * ai;
        are_s[n] = dar;
        aim_s[n] = dai;
        // Cd = (Cre + i Cim) * (exp(dtA) - 1) / A
        float er = expf(dar);
        float wr = er * cosf(dai), wi = er * sinf(dai);
        float numr = wr - 1.0f, numi = wi;
        float den = ar * ar + ai * ai;
        float qr = (numr * ar + numi * ai) / den;
        float qi = (numi * ar - numr * ai) / den;
        float cr = Cre[h * 32 + n], ci = Cim[h * 32 + n];
        float cdr = cr * qr - ci * qi;
        float cdi = cr * qi + ci * qr;
        cdr_s[n] = cdr;
        cdi_s[n] = cdi;
        ws[OFF_CD + (h * 32 + n) * 2] = cdr;
        ws[OFF_CD + (h * 32 + n) * 2 + 1] = cdi;
    }
    __syncthreads();
    // lo[n][r] = w^r, r=0..15
    for (int id = t; id < 512; id += 256) {
        int n = id >> 4, r = id & 15;
        float fr = (float)r;
        float e = expf(are_s[n] * fr);
        ws[OFF_LO + ((h * 32 + n) * 16 + r) * 2] = e * cosf(aim_s[n] * fr);
        ws[OFF_LO + ((h * 32 + n) * 16 + r) * 2 + 1] = e * sinf(aim_s[n] * fr);
    }
    // hi[n][q] = w^(16q), q=0..16  (hi[16] = w^256 = w^CHK)
    for (int id = t; id < 544; id += 256) {
        int n = id / 17, q = id - n * 17;
        float fq = 16.0f * (float)q;
        float e = expf(are_s[n] * fq);
        ws[OFF_HI + ((h * 32 + n) * 17 + q) * 2] = e * cosf(aim_s[n] * fq);
        ws[OFF_HI + ((h * 32 + n) * 17 + q) * 2 + 1] = e * sinf(aim_s[n] * fq);
    }
    // K[d] = 2 Re sum_n Cd_n w^d, d=0..CHK-1
    for (int d = t; d < CHK; d += 256) {
        float fd = (float)d;
        float acc = 0.f;
        for (int n = 0; n < 32; ++n) {
            float e = expf(are_s[n] * fd);
            float wr = e * cosf(aim_s[n] * fd);
            float wi = e * sinf(aim_s[n] * fd);
            acc += 2.0f * (cdr_s[n] * wr - cdi_s[n] * wi);
        }
        ws[OFF_K + h * CHK + d] = acc;
    }
}

// ---------------------------------------------------------------------------
// Kernel A: u = gelu(W_lin @ x + b_lin)   (pointwise over l, mixes channels)
// ---------------------------------------------------------------------------
__global__ void k_ulin(const float* __restrict__ x, const float* __restrict__ W,
                       const float* __restrict__ bl, float* __restrict__ ws) {
    __shared__ float W_s[1024];
    __shared__ float b_s[32];
    int t = threadIdx.x;
    for (int i = t; i < 1024; i += 256) W_s[i] = W[i];
    if (t < 32) b_s[t] = bl[t];
    __syncthreads();
    int blk = blockIdx.x;
    int b = blk >> 7;
    int l = ((blk & 127) << 8) + t;
    const float* xp = x + b * Hc * Lc + l;
    float xv[32];
#pragma unroll
    for (int h = 0; h < 32; ++h) xv[h] = xp[h * Lc];
    float* up = ws + OFF_U + b * Hc * Lc + l;
#pragma unroll
    for (int g = 0; g < 32; ++g) {
        float acc = b_s[g];
#pragma unroll
        for (int h = 0; h < 32; ++h) acc = fmaf(W_s[g * 32 + h], xv[h], acc);
        up[g * Lc] = gelu_f(acc);
    }
}

// ---------------------------------------------------------------------------
// Kernel S: chunk-level state scan. One block per (b,h); 4 chunks/iteration.
// Writes Sin[c] = state entering chunk c (s at index c*CHK-1).
// ---------------------------------------------------------------------------
__global__ void k_scan(float* __restrict__ ws) {
    int bh = blockIdx.x;
    int h = bh & 31;
    int t = threadIdx.x;
    __shared__ float u_s[1024];
    __shared__ float lo_s[32 * 34];   // [n] stride 34 words (17 cplx)
    __shared__ float hi_s[32 * 36];   // [n] stride 36 words (18 cplx)
    __shared__ float p16_s[64 * 66];  // [(cc*16+qq)] stride 66 words (33 cplx)
    for (int id = t; id < 512; id += 256) {
        int n = id >> 4, r = id & 15;
        lo_s[n * 34 + 2 * r] = ws[OFF_LO + ((h * 32 + n) * 16 + r) * 2];
        lo_s[n * 34 + 2 * r + 1] = ws[OFF_LO + ((h * 32 + n) * 16 + r) * 2 + 1];
    }
    for (int id = t; id < 544; id += 256) {
        int n = id / 17, q = id - n * 17;
        hi_s[n * 36 + 2 * q] = ws[OFF_HI + ((h * 32 + n) * 17 + q) * 2];
        hi_s[n * 36 + 2 * q + 1] = ws[OFF_HI + ((h * 32 + n) * 17 + q) * 2 + 1];
    }
    __syncthreads();
    float Sr = 0.f, Si = 0.f, wcr = 0.f, wci = 0.f;
    if (t < 32) {
        wcr = hi_s[t * 36 + 32];  // w^256
        wci = hi_s[t * 36 + 33];
    }
    const float* u = ws + OFF_U + bh * Lc;
    float* sinp = ws + OFF_SIN + bh * NCH * 64;
    for (int c0 = 0; c0 < NCH; c0 += 4) {
        // load 4 chunks of u (1024 floats)
        float4 uv = *(const float4*)(u + c0 * CHK + t * 4);
        *(float4*)(u_s + t * 4) = uv;
        __syncthreads();
        // stage 1: p16[cc][qq][n] = sum_rr lo[15-rr] * u[cc*256 + qq*16 + rr]
        for (int i = 0; i < 8; ++i) {
            int task = t + 256 * i;
            int cc = task >> 9;
            int id = task & 511;
            int n = id & 31, qq = id >> 5;
            const float* ub = u_s + cc * 256 + qq * 16;
            float pr = 0.f, pi = 0.f;
#pragma unroll
            for (int rr = 0; rr < 16; ++rr) {
                float uu = ub[rr];
                float lr = lo_s[n * 34 + 2 * (15 - rr)];
                float li = lo_s[n * 34 + 2 * (15 - rr) + 1];
                pr = fmaf(lr, uu, pr);
                pi = fmaf(li, uu, pi);
            }
            p16_s[(cc * 16 + qq) * 66 + 2 * n] = pr;
            p16_s[(cc * 16 + qq) * 66 + 2 * n + 1] = pi;
        }
        __syncthreads();
        // stage 2 (32 threads): P = sum_qq hi[15-qq]*p16[qq]; store Sin; S = wC*S + P
        if (t < 32) {
            int n = t;
#pragma unroll
            for (int cc = 0; cc < 4; ++cc) {
                float Pr = 0.f, Pi = 0.f;
#pragma unroll
                for (int qq = 0; qq < 16; ++qq) {
                    float hr = hi_s[n * 36 + 2 * (15 - qq)];
                    float hx = hi_s[n * 36 + 2 * (15 - qq) + 1];
                    float pr = p16_s[(cc * 16 + qq) * 66 + 2 * n];
                    float px = p16_s[(cc * 16 + qq) * 66 + 2 * n + 1];
                    Pr += hr * pr - hx * px;
                    Pi += hr * px + hx * pr;
                }
                int c = c0 + cc;
                sinp[c * 64 + 2 * n] = Sr;
                sinp[c * 64 + 2 * n + 1] = Si;
                float nSr = wcr * Sr - wci * Si + Pr;
                float nSi = wcr * Si + wci * Sr + Pi;
                Sr = nSr;
                Si = nSi;
            }
        }
        __syncthreads();  // p16 reuse vs next stage1 (and u_s reload)
    }
}

// ---------------------------------------------------------------------------
// Kernel E: per-chunk SSM output: y = local_conv(K,u) + carry(Sin) + D*u
// One block (256 thr) per (b,h,chunk); thread t owns output m=t.
// Writes y_ssm into d_out (scratch use; fully overwritten later by k_final).
// ---------------------------------------------------------------------------
__global__ void k_ssm(const float* __restrict__ Dp, float* __restrict__ ws,
                      float* __restrict__ ybuf) {
    int blk = blockIdx.x;  // ((b*32+h)*128 + c)
    int c = blk & 127;
    int bh = blk >> 7;
    int h = bh & 31;
    int t = threadIdx.x;
    __shared__ float u_s[264];         // 4 leading zeros + 256
    __shared__ float K_s[256];
    __shared__ float lo_s[16 * 66];    // [r] stride 66 words
    __shared__ float GH_s[17 * 66];    // [q] stride 66 words
    __shared__ float g_s[64];
    const float* u = ws + OFF_U + bh * Lc + c * CHK;
    u_s[4 + t] = u[t];
    if (t < 4) u_s[t] = 0.f;
    K_s[t] = ws[OFF_K + h * CHK + t];
    for (int id = t; id < 512; id += 256) {
        int n = id >> 4, r = id & 15;
        lo_s[r * 66 + 2 * n] = ws[OFF_LO + ((h * 32 + n) * 16 + r) * 2];
        lo_s[r * 66 + 2 * n + 1] = ws[OFF_LO + ((h * 32 + n) * 16 + r) * 2 + 1];
    }
    if (t < 32) {
        int n = t;
        float sr = ws[OFF_SIN + (bh * NCH + c) * 64 + 2 * n];
        float si = ws[OFF_SIN + (bh * NCH + c) * 64 + 2 * n + 1];
        float cdr = ws[OFF_CD + (h * 32 + n) * 2];
        float cdi = ws[OFF_CD + (h * 32 + n) * 2 + 1];
        g_s[2 * n] = cdr * sr - cdi * si;
        g_s[2 * n + 1] = cdr * si + cdi * sr;
    }
    __syncthreads();
    // GH[q][n] = G_n * hi[q][n]
    for (int id = t; id < 544; id += 256) {
        int q = id >> 5, n = id & 31;
        float hr = ws[OFF_HI + ((h * 32 + n) * 17 + q) * 2];
        float hx = ws[OFF_HI + ((h * 32 + n) * 17 + q) * 2 + 1];
        float gr = g_s[2 * n], gi = g_s[2 * n + 1];
        GH_s[q * 66 + 2 * n] = gr * hr - gi * hx;
        GH_s[q * 66 + 2 * n + 1] = gr * hx + gi * hr;
    }
    __syncthreads();
    // in-chunk causal conv: acc = sum_{d<=t} K[d]*u[t-d]  (zero-pad absorbs d>t)
    float acc = 0.f;
    int nt = (t + 4) & ~3;
    for (int d = 0; d < nt; d += 4) {
#pragma unroll
        for (int k = 0; k < 4; ++k) acc = fmaf(K_s[d + k], u_s[4 + t - d - k], acc);
    }
    // carry: 2*Re( sum_n G_n * w^(t+1) ),  w^(t+1) = hi[q]*lo[r]
    int q = (t + 1) >> 4, r = (t + 1) & 15;
    const float* ghp = GH_s + q * 66;
    const float* lop = lo_s + r * 66;
    float car = 0.f;
#pragma unroll
    for (int n = 0; n < 32; ++n)
        car += ghp[2 * n] * lop[2 * n] - ghp[2 * n + 1] * lop[2 * n + 1];
    float yv = acc + 2.f * car + Dp[h] * u_s[4 + t];
    ybuf[bh * Lc + c * CHK + t] = yv;
}

// ---------------------------------------------------------------------------
// Kernel F: z = W_out @ y + b_out (64 ch); yg = z1 * sigmoid(z2) -> into u buf
// ---------------------------------------------------------------------------
__global__ void k_glu(const float* __restrict__ Wout, const float* __restrict__ bout,
                      const float* __restrict__ ybuf, float* __restrict__ ws) {
    __shared__ float W_s[2048];
    __shared__ float b_s[64];
    int t = threadIdx.x;
    for (int i = t; i < 2048; i += 256) W_s[i] = Wout[i];
    if (t < 64) b_s[t] = bout[t];
    __syncthreads();
    int blk = blockIdx.x;
    int b = blk >> 7;
    int l = ((blk & 127) << 8) + t;
    const float* yp = ybuf + b * Hc * Lc + l;
    float yv[32];
#pragma unroll
    for (int h = 0; h < 32; ++h) yv[h] = yp[h * Lc];
    float* op = ws + OFF_U + b * Hc * Lc + l;  // yg overwrites u (dead)
#pragma unroll
    for (int g = 0; g < 32; ++g) {
        float a1 = b_s[g], a2 = b_s[g + 32];
#pragma unroll
        for (int h = 0; h < 32; ++h) {
            a1 = fmaf(W_s[g * 32 + h], yv[h], a1);
            a2 = fmaf(W_s[(g + 32) * 32 + h], yv[h], a2);
        }
        float sg = 1.f / (1.f + expf(-a2));
        op[g * Lc] = a1 * sg;
    }
}

// ---------------------------------------------------------------------------
// Kernel R: per-channel partial sums for BatchNorm stats
// ---------------------------------------------------------------------------
__global__ void k_stats(float* __restrict__ ws) {
    int blk = blockIdx.x;  // g*8 + s
    int g = blk >> 3, s = blk & 7;
    int t = threadIdx.x;
    float s1 = 0.f, s2 = 0.f;
    const float* yg = ws + OFF_U;
    for (int b = 0; b < 8; ++b) {
        const float* p = yg + b * Hc * Lc + g * Lc + s * 4096 + t * 16;
#pragma unroll
        for (int j = 0; j < 4; ++j) {
            float4 v = *(const float4*)(p + j * 4);
            s1 += v.x + v.y + v.z + v.w;
            s2 += v.x * v.x + v.y * v.y + v.z * v.z + v.w * v.w;
        }
    }
    __shared__ float r1[256], r2[256];
    r1[t] = s1;
    r2[t] = s2;
    __syncthreads();
    for (int off = 128; off > 0; off >>= 1) {
        if (t < off) {
            r1[t] += r1[t + off];
            r2[t] += r2[t + off];
        }
        __syncthreads();
    }
    if (t == 0) {
        ws[OFF_SUMP + blk] = r1[0];
        ws[OFF_SQP + blk] = r2[0];
    }
}

// ---------------------------------------------------------------------------
// Kernel G: finalize BN stats + FiLM projection gb = cond @ film_W^T + film_b
// ---------------------------------------------------------------------------
__global__ void k_finalize(const float* __restrict__ cond, const float* __restrict__ filmW,
                           const float* __restrict__ filmb, float* __restrict__ ws) {
    int t = threadIdx.x;
    if (t < 32) {
        float su = 0.f, sq = 0.f;
        for (int s = 0; s < 8; ++s) {
            su += ws[OFF_SUMP + t * 8 + s];
            sq += ws[OFF_SQP + t * 8 + s];
        }
        float inv_cnt = 1.0f / (float)(Bsz * Lc);
        float mean = su * inv_cnt;
        float var = sq * inv_cnt - mean * mean;
        ws[OFF_MEAN + t] = mean;
        ws[OFF_INV + t] = rsqrtf(var + 1e-5f);
    }
    for (int id = t; id < 512; id += 256) {
        int b = id >> 6, j = id & 63;
        float acc = filmb[j];
        for (int k = 0; k < 128; ++k) acc = fmaf(cond[b * 128 + k], filmW[j * 128 + k], acc);
        ws[OFF_GB + id] = acc;
    }
}

// ---------------------------------------------------------------------------
// Kernel H: out = gelu(gamma*(yg-mean)*inv + beta) + res_w * x
// ---------------------------------------------------------------------------
__global__ void k_final(const float* __restrict__ x, const float* __restrict__ resw,
                        const float* __restrict__ ws, float* __restrict__ out) {
    int i = blockIdx.x * 256 + threadIdx.x;  // over 2097152 float4 groups
    int l4 = i & 8191;
    int hl = i >> 13;
    int h = hl & 31;
    int b = hl >> 5;
    float mean = ws[OFF_MEAN + h], inv = ws[OFF_INV + h];
    float gam = ws[OFF_GB + b * 64 + h], bet = ws[OFF_GB + b * 64 + 32 + h];
    float rw = resw[h];
    int base = hl * Lc + l4 * 4;
    float4 yv = *(const float4*)(ws + OFF_U + base);
    float4 xv = *(const float4*)(x + base);
    float4 o;
    o.x = gelu_f(fmaf(gam, (yv.x - mean) * inv, bet)) + rw * xv.x;
    o.y = gelu_f(fmaf(gam, (yv.y - mean) * inv, bet)) + rw * xv.y;
    o.z = gelu_f(fmaf(gam, (yv.z - mean) * inv, bet)) + rw * xv.z;
    o.w = gelu_f(fmaf(gam, (yv.w - mean) * inv, bet)) + rw * xv.w;
    *(float4*)(out + base) = o;
}

// ---------------------------------------------------------------------------
extern "C" void kernel_launch(void* const* d_in, const int* in_sizes, int n_in,
                              void* d_out, int out_size, void* d_ws, size_t ws_size,
                              hipStream_t stream) {
    const float* x = (const float*)d_in[0];
    const float* cond = (const float*)d_in[1];
    const float* W_lin = (const float*)d_in[2];
    const float* b_lin = (const float*)d_in[3];
    const float* log_dt = (const float*)d_in[4];
    const float* A_re = (const float*)d_in[5];
    const float* A_im = (const float*)d_in[6];
    const float* C_re = (const float*)d_in[7];
    const float* C_im = (const float*)d_in[8];
    const float* Dp = (const float*)d_in[9];
    const float* W_out = (const float*)d_in[10];
    const float* b_out = (const float*)d_in[11];
    const float* film_W = (const float*)d_in[12];
    const float* film_b = (const float*)d_in[13];
    const float* res_w = (const float*)d_in[14];
    float* ws = (float*)d_ws;
    float* out = (float*)d_out;

    hipLaunchKernelGGL(k_tables, dim3(32), dim3(256), 0, stream, log_dt, A_re, A_im, C_re, C_im, ws);
    hipLaunchKernelGGL(k_ulin, dim3(1024), dim3(256), 0, stream, x, W_lin, b_lin, ws);
    hipLaunchKernelGGL(k_scan, dim3(256), dim3(256), 0, stream, ws);
    hipLaunchKernelGGL(k_ssm, dim3(Bsz * Hc * NCH), dim3(256), 0, stream, Dp, ws, out);
    hipLaunchKernelGGL(k_glu, dim3(1024), dim3(256), 0, stream, W_out, b_out, out, ws);
    hipLaunchKernelGGL(k_stats, dim3(256), dim3(256), 0, stream, ws);
    hipLaunchKernelGGL(k_finalize, dim3(1), dim3(256), 0, stream, cond, film_W, film_b, ws);
    hipLaunchKernelGGL(k_final, dim3(8192), dim3(256), 0, stream, x, res_w, ws, out);
}

// Round 7
// 370.393 us; speedup vs baseline: 1.2634x; 1.2634x over previous
//
#include <hip/hip_runtime.h>
#include <math.h>

#define Bsz 8
#define Hc 32
#define Lc 32768
#define Nst 32
#define CDc 128
#define CHK 256
#define NCH (Lc / CHK) /* 128 */

// ---- workspace layout (float offsets) ----  total 10564672 floats = 42.3 MB
// (y_ssm intermediate lives in d_out, NOT here, to keep ws small)
#define OFF_U 0            /* u[B][H][L]          8388608 (reused for yg after k_glu) */
#define OFF_SIN 8388608    /* P then Sin [B*H][NCH][N][2]  2097152 */
#define OFF_K 10485760     /* K_local[H][CHK]     8192    */
#define OFF_LO 10493952    /* lo[H][N][16][2]     32768   */
#define OFF_HI 10526720    /* hi[H][N][17][2]     34816   */
#define OFF_CD 10561536    /* Cd[H][N][2]         2048    */
#define OFF_SUMP 10563584  /* [32][8]             256     */
#define OFF_SQP 10563840   /* [32][8]             256     */
#define OFF_MEAN 10564096  /* [32]                32      */
#define OFF_INV 10564128   /* [32]                32      */
#define OFF_GB 10564160    /* gb[B][64]           512     */

__device__ __forceinline__ float gelu_f(float v) {
    const float c = 0.7978845608028654f;
    return 0.5f * v * (1.0f + tanhf(c * (v + 0.044715f * v * v * v)));
}

// ---------------------------------------------------------------------------
// Kernel B: per-(h,n) discretization + power tables + short local kernel K
// ---------------------------------------------------------------------------
__global__ void k_tables(const float* __restrict__ logdt, const float* __restrict__ Are,
                         const float* __restrict__ Aim, const float* __restrict__ Cre,
                         const float* __restrict__ Cim, float* __restrict__ ws) {
    int h = blockIdx.x;
    int t = threadIdx.x;
    __shared__ float are_s[32], aim_s[32], cdr_s[32], cdi_s[32];
    if (t < 32) {
        int n = t;
        float dt = expf(logdt[h]);
        float ar = Are[h * 32 + n], ai = Aim[h * 32 + n];
        float dar = dt * ar, dai = dt * ai;
        are_s[n] = dar;
        aim_s[n] = dai;
        // Cd = (Cre + i Cim) * (exp(dtA) - 1) / A
        float er = expf(dar);
        float wr = er * cosf(dai), wi = er * sinf(dai);
        float numr = wr - 1.0f, numi = wi;
        float den = ar * ar + ai * ai;
        float qr = (numr * ar + numi * ai) / den;
        float qi = (numi * ar - numr * ai) / den;
        float cr = Cre[h * 32 + n], ci = Cim[h * 32 + n];
        float cdr = cr * qr - ci * qi;
        float cdi = cr * qi + ci * qr;
        cdr_s[n] = cdr;
        cdi_s[n] = cdi;
        ws[OFF_CD + (h * 32 + n) * 2] = cdr;
        ws[OFF_CD + (h * 32 + n) * 2 + 1] = cdi;
    }
    __syncthreads();
    // lo[n][r] = w^r, r=0..15
    for (int id = t; id < 512; id += 256) {
        int n = id >> 4, r = id & 15;
        float fr = (float)r;
        float e = expf(are_s[n] * fr);
        ws[OFF_LO + ((h * 32 + n) * 16 + r) * 2] = e * cosf(aim_s[n] * fr);
        ws[OFF_LO + ((h * 32 + n) * 16 + r) * 2 + 1] = e * sinf(aim_s[n] * fr);
    }
    // hi[n][q] = w^(16q), q=0..16  (hi[16] = w^256 = w^CHK)
    for (int id = t; id < 544; id += 256) {
        int n = id / 17, q = id - n * 17;
        float fq = 16.0f * (float)q;
        float e = expf(are_s[n] * fq);
        ws[OFF_HI + ((h * 32 + n) * 17 + q) * 2] = e * cosf(aim_s[n] * fq);
        ws[OFF_HI + ((h * 32 + n) * 17 + q) * 2 + 1] = e * sinf(aim_s[n] * fq);
    }
    // K[d] = 2 Re sum_n Cd_n w^d, d=0..CHK-1
    for (int d = t; d < CHK; d += 256) {
        float fd = (float)d;
        float acc = 0.f;
        for (int n = 0; n < 32; ++n) {
            float e = expf(are_s[n] * fd);
            float wr = e * cosf(aim_s[n] * fd);
            float wi = e * sinf(aim_s[n] * fd);
            acc += 2.0f * (cdr_s[n] * wr - cdi_s[n] * wi);
        }
        ws[OFF_K + h * CHK + d] = acc;
    }
}

// ---------------------------------------------------------------------------
// Kernel A: u = gelu(W_lin @ x + b_lin)   (pointwise over l, mixes channels)
// ---------------------------------------------------------------------------
__global__ void k_ulin(const float* __restrict__ x, const float* __restrict__ W,
                       const float* __restrict__ bl, float* __restrict__ ws) {
    __shared__ float W_s[1024];
    __shared__ float b_s[32];
    int t = threadIdx.x;
    for (int i = t; i < 1024; i += 256) W_s[i] = W[i];
    if (t < 32) b_s[t] = bl[t];
    __syncthreads();
    int blk = blockIdx.x;
    int b = blk >> 7;
    int l = ((blk & 127) << 8) + t;
    const float* xp = x + b * Hc * Lc + l;
    float xv[32];
#pragma unroll
    for (int h = 0; h < 32; ++h) xv[h] = xp[h * Lc];
    float* up = ws + OFF_U + b * Hc * Lc + l;
#pragma unroll
    for (int g = 0; g < 32; ++g) {
        float acc = b_s[g];
#pragma unroll
        for (int h = 0; h < 32; ++h) acc = fmaf(W_s[g * 32 + h], xv[h], acc);
        up[g * Lc] = gelu_f(acc);
    }
}

// ---------------------------------------------------------------------------
// Kernel S1: per-chunk reduction P[c][n] = sum_{j<256} w^(255-j) u[c*256+j].
// Grid 8192: block = (bh, group of 4 chunks). Full occupancy, b128 LDS reads.
// Writes P into the OFF_SIN buffer (converted in-place to Sin by k_scanS).
// ---------------------------------------------------------------------------
__global__ void k_scanP(float* __restrict__ ws) {
    int g = blockIdx.x;
    int bh = g >> 5;
    int c0 = (g & 31) << 2;
    int h = bh & 31;
    int t = threadIdx.x;
    __shared__ float u_s[1024];
    __shared__ float lo_s[32 * 34];   // [n] stride 34
    __shared__ float hi_s[32 * 36];   // [n] stride 36
    __shared__ float p16_s[64 * 66];  // [(cc*16+qq)] stride 66
    {
        float4 v = *(const float4*)(ws + OFF_U + bh * Lc + (c0 << 8) + 4 * t);
        *(float4*)(u_s + 4 * t) = v;
    }
    for (int id = t; id < 512; id += 256) {
        int n = id >> 4, r = id & 15;
        lo_s[n * 34 + 2 * r] = ws[OFF_LO + ((h * 32 + n) * 16 + r) * 2];
        lo_s[n * 34 + 2 * r + 1] = ws[OFF_LO + ((h * 32 + n) * 16 + r) * 2 + 1];
    }
    for (int id = t; id < 544; id += 256) {
        int n = id / 17, q = id - n * 17;
        hi_s[n * 36 + 2 * q] = ws[OFF_HI + ((h * 32 + n) * 17 + q) * 2];
        hi_s[n * 36 + 2 * q + 1] = ws[OFF_HI + ((h * 32 + n) * 17 + q) * 2 + 1];
    }
    __syncthreads();
    int n = t & 31;
    // register-cache lo row for this thread's n
    float lor[16], loi[16];
#pragma unroll
    for (int r = 0; r < 16; ++r) {
        lor[r] = lo_s[n * 34 + 2 * r];
        loi[r] = lo_s[n * 34 + 2 * r + 1];
    }
#pragma unroll
    for (int i = 0; i < 8; ++i) {
        int x = (t >> 5) + (i << 3);  // x = cc*16+qq, 0..63
        const float* ub = u_s + (x << 4);
        float pr = 0.f, pi = 0.f;
#pragma unroll
        for (int k = 0; k < 4; ++k) {
            float4 uq = *(const float4*)(ub + (k << 2));
            pr = fmaf(lor[15 - 4 * k], uq.x, pr); pi = fmaf(loi[15 - 4 * k], uq.x, pi);
            pr = fmaf(lor[14 - 4 * k], uq.y, pr); pi = fmaf(loi[14 - 4 * k], uq.y, pi);
            pr = fmaf(lor[13 - 4 * k], uq.z, pr); pi = fmaf(loi[13 - 4 * k], uq.z, pi);
            pr = fmaf(lor[12 - 4 * k], uq.w, pr); pi = fmaf(loi[12 - 4 * k], uq.w, pi);
        }
        p16_s[x * 66 + 2 * n] = pr;
        p16_s[x * 66 + 2 * n + 1] = pi;
    }
    __syncthreads();
    if (t < 128) {
        int cc = t >> 5, nn = t & 31;
        float Pr = 0.f, Pi = 0.f;
#pragma unroll
        for (int qq = 0; qq < 16; ++qq) {
            float hr = hi_s[nn * 36 + 2 * (15 - qq)];
            float hx = hi_s[nn * 36 + 2 * (15 - qq) + 1];
            float pr = p16_s[(cc * 16 + qq) * 66 + 2 * nn];
            float px = p16_s[(cc * 16 + qq) * 66 + 2 * nn + 1];
            Pr += hr * pr - hx * px;
            Pi += hr * px + hx * pr;
        }
        ws[OFF_SIN + (bh * 128 + c0 + cc) * 64 + 2 * nn] = Pr;
        ws[OFF_SIN + (bh * 128 + c0 + cc) * 64 + 2 * nn + 1] = Pi;
    }
}

// ---------------------------------------------------------------------------
// Kernel S2: sequential chunk-state scan, in place: P[c] -> Sin[c].
// 8192 independent (bh,n) scans; Sin[c] = state entering chunk c.
// ---------------------------------------------------------------------------
__global__ void k_scanS(float* __restrict__ ws) {
    int tid = blockIdx.x * 256 + threadIdx.x;  // 0..8191
    int bh = tid >> 5;
    int n = tid & 31;
    int h = bh & 31;
    float wcr = ws[OFF_HI + ((h * 32 + n) * 17 + 16) * 2];
    float wci = ws[OFF_HI + ((h * 32 + n) * 17 + 16) * 2 + 1];
    float Sr = 0.f, Si = 0.f;
    float* base = ws + OFF_SIN + bh * (NCH * 64) + 2 * n;
    for (int c = 0; c < NCH; ++c) {
        float Pr = base[c * 64];
        float Pi = base[c * 64 + 1];
        base[c * 64] = Sr;
        base[c * 64 + 1] = Si;
        float nSr = wcr * Sr - wci * Si + Pr;
        Si = wcr * Si + wci * Sr + Pi;
        Sr = nSr;
    }
}

// ---------------------------------------------------------------------------
// Kernel E v2: per-chunk SSM output: y = local_conv(K,u) + carry(Sin) + D*u
// Block = (bh, 4 chunks); wave w handles chunk c0+w; lane l owns outputs
// m=4l..4l+3. Conv: rolling register window, b128 reads (16 FMA per 1 b128).
// Carry: w^(m+1) = hi[q']*lo[r'] per lane (broadcast reads), chained by *w.
// ---------------------------------------------------------------------------
__global__ void k_ssm(const float* __restrict__ Dp, float* __restrict__ ws,
                      float* __restrict__ ybuf) {
    int g = blockIdx.x;
    int bh = g >> 5;
    int c0 = (g & 31) << 2;
    int h = bh & 31;
    int t = threadIdx.x;
    __shared__ float u4_s[4 * 264];   // [cc][264]: 4 zero-pad + 256 u
    __shared__ float K_s[256];
    __shared__ float loT_s[16 * 66];  // [r][2n] r-major
    __shared__ float hiT_s[16 * 66];  // [q][2n] q-major
    __shared__ float Cd_s[64];
    __shared__ float Sin_s[256];      // [cc][64]
    {
        const float* up = ws + OFF_U + bh * Lc + (c0 << 8);
        float4 v = *(const float4*)(up + 4 * t);
        int cc = t >> 6;
        int i = (4 * t) & 255;
        *(float4*)(u4_s + cc * 264 + 4 + i) = v;
        if (t < 16) u4_s[(t >> 2) * 264 + (t & 3)] = 0.f;
    }
    K_s[t] = ws[OFF_K + (h << 8) + t];
    for (int id = t; id < 512; id += 256) {
        int n = id >> 4, r = id & 15;
        loT_s[r * 66 + 2 * n] = ws[OFF_LO + ((h * 32 + n) * 16 + r) * 2];
        loT_s[r * 66 + 2 * n + 1] = ws[OFF_LO + ((h * 32 + n) * 16 + r) * 2 + 1];
        hiT_s[r * 66 + 2 * n] = ws[OFF_HI + ((h * 32 + n) * 17 + r) * 2];
        hiT_s[r * 66 + 2 * n + 1] = ws[OFF_HI + ((h * 32 + n) * 17 + r) * 2 + 1];
    }
    if (t < 64) Cd_s[t] = ws[OFF_CD + (h << 6) + t];
    Sin_s[t] = ws[OFF_SIN + (bh * 128 + c0 + (t >> 6)) * 64 + (t & 63)];
    __syncthreads();
    int cc = t >> 6, l = t & 63;
    int m0 = l << 2;
    const float* ub = u4_s + cc * 264 + 4;
    // ---- in-chunk causal conv, 4 outputs, rolling window ----
    float a0 = 0.f, a1 = 0.f, a2 = 0.f, a3 = 0.f;
    float4 Bq = *(const float4*)(ub + m0);
    for (int d0 = 0; d0 <= m0; d0 += 4) {
        float4 Kq = *(const float4*)(K_s + d0);
        float4 Aq = *(const float4*)(ub + m0 - d0 - 4);
        // W[0..7] = {Aq.x..w, Bq.x..w};  y[m0+j] += K[d0+k]*W[4+j-k]
        a0 = fmaf(Kq.x, Bq.x, a0); a0 = fmaf(Kq.y, Aq.w, a0); a0 = fmaf(Kq.z, Aq.z, a0); a0 = fmaf(Kq.w, Aq.y, a0);
        a1 = fmaf(Kq.x, Bq.y, a1); a1 = fmaf(Kq.y, Bq.x, a1); a1 = fmaf(Kq.z, Aq.w, a1); a1 = fmaf(Kq.w, Aq.z, a1);
        a2 = fmaf(Kq.x, Bq.z, a2); a2 = fmaf(Kq.y, Bq.y, a2); a2 = fmaf(Kq.z, Bq.x, a2); a2 = fmaf(Kq.w, Aq.w, a2);
        a3 = fmaf(Kq.x, Bq.w, a3); a3 = fmaf(Kq.y, Bq.z, a3); a3 = fmaf(Kq.z, Bq.y, a3); a3 = fmaf(Kq.w, Bq.x, a3);
        Bq = Aq;
    }
    // ---- carry: car_j = Re sum_n Cd_n S_n w^(m0+1+j) ----
    int q1 = (m0 + 1) >> 4;
    int r1 = (m0 + 1) & 15;
    const float* hp = hiT_s + q1 * 66;
    const float* lp = loT_s + r1 * 66;
    const float* w1p = loT_s + 1 * 66;
    const float* sn = Sin_s + (cc << 6);
    float c0r = 0.f, c1r = 0.f, c2r = 0.f, c3r = 0.f;
#pragma unroll
    for (int n = 0; n < 32; ++n) {
        float hr = hp[2 * n], hi = hp[2 * n + 1];
        float lr = lp[2 * n], li = lp[2 * n + 1];
        float wqr = hr * lr - hi * li;
        float wqi = hr * li + hi * lr;           // w^(m0+1)
        float cdr = Cd_s[2 * n], cdi = Cd_s[2 * n + 1];
        float cwr = cdr * wqr - cdi * wqi;
        float cwi = cdr * wqi + cdi * wqr;       // Cd*w^(m0+1)
        float Sr = sn[2 * n], Si = sn[2 * n + 1];
        float zr = cwr * Sr - cwi * Si;
        float zi = cwr * Si + cwi * Sr;
        c0r += zr;
        float w1r = w1p[2 * n], w1i = w1p[2 * n + 1];
        float t1r = zr * w1r - zi * w1i, t1i = zr * w1i + zi * w1r;
        c1r += t1r;
        float t2r = t1r * w1r - t1i * w1i, t2i = t1r * w1i + t1i * w1r;
        c2r += t2r;
        float t3r = t2r * w1r - t2i * w1i;
        c3r += t3r;
    }
    // ---- combine + write ----
    float4 uq = *(const float4*)(ub + m0);
    float Dh = Dp[h];
    float4 o;
    o.x = a0 + 2.f * c0r + Dh * uq.x;
    o.y = a1 + 2.f * c1r + Dh * uq.y;
    o.z = a2 + 2.f * c2r + Dh * uq.z;
    o.w = a3 + 2.f * c3r + Dh * uq.w;
    *(float4*)(ybuf + bh * Lc + ((c0 + cc) << 8) + m0) = o;
}

// ---------------------------------------------------------------------------
// Kernel F: z = W_out @ y + b_out (64 ch); yg = z1 * sigmoid(z2) -> into u buf
// ---------------------------------------------------------------------------
__global__ void k_glu(const float* __restrict__ Wout, const float* __restrict__ bout,
                      const float* __restrict__ ybuf, float* __restrict__ ws) {
    __shared__ float W_s[2048];
    __shared__ float b_s[64];
    int t = threadIdx.x;
    for (int i = t; i < 2048; i += 256) W_s[i] = Wout[i];
    if (t < 64) b_s[t] = bout[t];
    __syncthreads();
    int blk = blockIdx.x;
    int b = blk >> 7;
    int l = ((blk & 127) << 8) + t;
    const float* yp = ybuf + b * Hc * Lc + l;
    float yv[32];
#pragma unroll
    for (int h = 0; h < 32; ++h) yv[h] = yp[h * Lc];
    float* op = ws + OFF_U + b * Hc * Lc + l;  // yg overwrites u (dead)
#pragma unroll
    for (int g = 0; g < 32; ++g) {
        float a1 = b_s[g], a2 = b_s[g + 32];
#pragma unroll
        for (int h = 0; h < 32; ++h) {
            a1 = fmaf(W_s[g * 32 + h], yv[h], a1);
            a2 = fmaf(W_s[(g + 32) * 32 + h], yv[h], a2);
        }
        float sg = 1.f / (1.f + expf(-a2));
        op[g * Lc] = a1 * sg;
    }
}

// ---------------------------------------------------------------------------
// Kernel R: per-channel partial sums for BatchNorm stats
// ---------------------------------------------------------------------------
__global__ void k_stats(float* __restrict__ ws) {
    int blk = blockIdx.x;  // g*8 + s
    int g = blk >> 3, s = blk & 7;
    int t = threadIdx.x;
    float s1 = 0.f, s2 = 0.f;
    const float* yg = ws + OFF_U;
    for (int b = 0; b < 8; ++b) {
        const float* p = yg + b * Hc * Lc + g * Lc + s * 4096 + t * 16;
#pragma unroll
        for (int j = 0; j < 4; ++j) {
            float4 v = *(const float4*)(p + j * 4);
            s1 += v.x + v.y + v.z + v.w;
            s2 += v.x * v.x + v.y * v.y + v.z * v.z + v.w * v.w;
        }
    }
    __shared__ float r1[256], r2[256];
    r1[t] = s1;
    r2[t] = s2;
    __syncthreads();
    for (int off = 128; off > 0; off >>= 1) {
        if (t < off) {
            r1[t] += r1[t + off];
            r2[t] += r2[t + off];
        }
        __syncthreads();
    }
    if (t == 0) {
        ws[OFF_SUMP + blk] = r1[0];
        ws[OFF_SQP + blk] = r2[0];
    }
}

// ---------------------------------------------------------------------------
// Kernel G: finalize BN stats + FiLM projection gb = cond @ film_W^T + film_b
// ---------------------------------------------------------------------------
__global__ void k_finalize(const float* __restrict__ cond, const float* __restrict__ filmW,
                           const float* __restrict__ filmb, float* __restrict__ ws) {
    int t = threadIdx.x;
    if (t < 32) {
        float su = 0.f, sq = 0.f;
        for (int s = 0; s < 8; ++s) {
            su += ws[OFF_SUMP + t * 8 + s];
            sq += ws[OFF_SQP + t * 8 + s];
        }
        float inv_cnt = 1.0f / (float)(Bsz * Lc);
        float mean = su * inv_cnt;
        float var = sq * inv_cnt - mean * mean;
        ws[OFF_MEAN + t] = mean;
        ws[OFF_INV + t] = rsqrtf(var + 1e-5f);
    }
    for (int id = t; id < 512; id += 256) {
        int b = id >> 6, j = id & 63;
        float acc = filmb[j];
        for (int k = 0; k < 128; ++k) acc = fmaf(cond[b * 128 + k], filmW[j * 128 + k], acc);
        ws[OFF_GB + id] = acc;
    }
}

// ---------------------------------------------------------------------------
// Kernel H: out = gelu(gamma*(yg-mean)*inv + beta) + res_w * x
// ---------------------------------------------------------------------------
__global__ void k_final(const float* __restrict__ x, const float* __restrict__ resw,
                        const float* __restrict__ ws, float* __restrict__ out) {
    int i = blockIdx.x * 256 + threadIdx.x;  // over 2097152 float4 groups
    int l4 = i & 8191;
    int hl = i >> 13;
    int h = hl & 31;
    int b = hl >> 5;
    float mean = ws[OFF_MEAN + h], inv = ws[OFF_INV + h];
    float gam = ws[OFF_GB + b * 64 + h], bet = ws[OFF_GB + b * 64 + 32 + h];
    float rw = resw[h];
    int base = hl * Lc + l4 * 4;
    float4 yv = *(const float4*)(ws + OFF_U + base);
    float4 xv = *(const float4*)(x + base);
    float4 o;
    o.x = gelu_f(fmaf(gam, (yv.x - mean) * inv, bet)) + rw * xv.x;
    o.y = gelu_f(fmaf(gam, (yv.y - mean) * inv, bet)) + rw * xv.y;
    o.z = gelu_f(fmaf(gam, (yv.z - mean) * inv, bet)) + rw * xv.z;
    o.w = gelu_f(fmaf(gam, (yv.w - mean) * inv, bet)) + rw * xv.w;
    *(float4*)(out + base) = o;
}

// ---------------------------------------------------------------------------
extern "C" void kernel_launch(void* const* d_in, const int* in_sizes, int n_in,
                              void* d_out, int out_size, void* d_ws, size_t ws_size,
                              hipStream_t stream) {
    const float* x = (const float*)d_in[0];
    const float* cond = (const float*)d_in[1];
    const float* W_lin = (const float*)d_in[2];
    const float* b_lin = (const float*)d_in[3];
    const float* log_dt = (const float*)d_in[4];
    const float* A_re = (const float*)d_in[5];
    const float* A_im = (const float*)d_in[6];
    const float* C_re = (const float*)d_in[7];
    const float* C_im = (const float*)d_in[8];
    const float* Dp = (const float*)d_in[9];
    const float* W_out = (const float*)d_in[10];
    const float* b_out = (const float*)d_in[11];
    const float* film_W = (const float*)d_in[12];
    const float* film_b = (const float*)d_in[13];
    const float* res_w = (const float*)d_in[14];
    float* ws = (float*)d_ws;
    float* out = (float*)d_out;

    hipLaunchKernelGGL(k_tables, dim3(32), dim3(256), 0, stream, log_dt, A_re, A_im, C_re, C_im, ws);
    hipLaunchKernelGGL(k_ulin, dim3(1024), dim3(256), 0, stream, x, W_lin, b_lin, ws);
    hipLaunchKernelGGL(k_scanP, dim3(8192), dim3(256), 0, stream, ws);
    hipLaunchKernelGGL(k_scanS, dim3(32), dim3(256), 0, stream, ws);
    hipLaunchKernelGGL(k_ssm, dim3(8192), dim3(256), 0, stream, Dp, ws, out);
    hipLaunchKernelGGL(k_glu, dim3(1024), dim3(256), 0, stream, W_out, b_out, out, ws);
    hipLaunchKernelGGL(k_stats, dim3(256), dim3(256), 0, stream, ws);
    hipLaunchKernelGGL(k_finalize, dim3(1), dim3(256), 0, stream, cond, film_W, film_b, ws);
    hipLaunchKernelGGL(k_final, dim3(8192), dim3(256), 0, stream, x, res_w, ws, out);
}

// Round 8
// 358.946 us; speedup vs baseline: 1.3037x; 1.0319x over previous
//
#include <hip/hip_runtime.h>
#include <math.h>

#define Bsz 8
#define Hc 32
#define Lc 32768
#define Nst 32
#define CDc 128
#define CHK 256
#define NCH (Lc / CHK) /* 128 */

// ---- workspace layout (float offsets) ----  total 10564672 floats = 42.3 MB
// (y_ssm intermediate lives in d_out, NOT here, to keep ws small)
#define OFF_U 0            /* u[B][H][L]          8388608 (reused for yg after k_glu) */
#define OFF_SIN 8388608    /* P/Sin [c][bh][n][2] 2097152 (c-major, transposed) */
#define OFF_K 10485760     /* K_local[H][CHK]     8192    */
#define OFF_LO 10493952    /* lo[H][N][16][2]     32768   */
#define OFF_HI 10526720    /* hi[H][N][17][2]     34816   */
#define OFF_CD 10561536    /* Cd[H][N][2]         2048    */
#define OFF_SUMP 10563584  /* [32][8]             256     */
#define OFF_SQP 10563840   /* [32][8]             256     */
#define OFF_MEAN 10564096  /* [32]                32      */
#define OFF_INV 10564128   /* [32]                32      */
#define OFF_GB 10564160    /* gb[B][64]           512     */

__device__ __forceinline__ float gelu_f(float v) {
    const float c = 0.7978845608028654f;
    return 0.5f * v * (1.0f + tanhf(c * (v + 0.044715f * v * v * v)));
}

// ---------------------------------------------------------------------------
// Kernel B: per-(h,n) discretization + power tables + short local kernel K
// ---------------------------------------------------------------------------
__global__ void k_tables(const float* __restrict__ logdt, const float* __restrict__ Are,
                         const float* __restrict__ Aim, const float* __restrict__ Cre,
                         const float* __restrict__ Cim, float* __restrict__ ws) {
    int h = blockIdx.x;
    int t = threadIdx.x;
    __shared__ float are_s[32], aim_s[32], cdr_s[32], cdi_s[32];
    if (t < 32) {
        int n = t;
        float dt = expf(logdt[h]);
        float ar = Are[h * 32 + n], ai = Aim[h * 32 + n];
        float dar = dt * ar, dai = dt * ai;
        are_s[n] = dar;
        aim_s[n] = dai;
        // Cd = (Cre + i Cim) * (exp(dtA) - 1) / A
        float er = expf(dar);
        float wr = er * cosf(dai), wi = er * sinf(dai);
        float numr = wr - 1.0f, numi = wi;
        float den = ar * ar + ai * ai;
        float qr = (numr * ar + numi * ai) / den;
        float qi = (numi * ar - numr * ai) / den;
        float cr = Cre[h * 32 + n], ci = Cim[h * 32 + n];
        float cdr = cr * qr - ci * qi;
        float cdi = cr * qi + ci * qr;
        cdr_s[n] = cdr;
        cdi_s[n] = cdi;
        ws[OFF_CD + (h * 32 + n) * 2] = cdr;
        ws[OFF_CD + (h * 32 + n) * 2 + 1] = cdi;
    }
    __syncthreads();
    // lo[n][r] = w^r, r=0..15
    for (int id = t; id < 512; id += 256) {
        int n = id >> 4, r = id & 15;
        float fr = (float)r;
        float e = expf(are_s[n] * fr);
        ws[OFF_LO + ((h * 32 + n) * 16 + r) * 2] = e * cosf(aim_s[n] * fr);
        ws[OFF_LO + ((h * 32 + n) * 16 + r) * 2 + 1] = e * sinf(aim_s[n] * fr);
    }
    // hi[n][q] = w^(16q), q=0..16  (hi[16] = w^256 = w^CHK)
    for (int id = t; id < 544; id += 256) {
        int n = id / 17, q = id - n * 17;
        float fq = 16.0f * (float)q;
        float e = expf(are_s[n] * fq);
        ws[OFF_HI + ((h * 32 + n) * 17 + q) * 2] = e * cosf(aim_s[n] * fq);
        ws[OFF_HI + ((h * 32 + n) * 17 + q) * 2 + 1] = e * sinf(aim_s[n] * fq);
    }
    // K[d] = 2 Re sum_n Cd_n w^d, d=0..CHK-1
    for (int d = t; d < CHK; d += 256) {
        float fd = (float)d;
        float acc = 0.f;
        for (int n = 0; n < 32; ++n) {
            float e = expf(are_s[n] * fd);
            float wr = e * cosf(aim_s[n] * fd);
            float wi = e * sinf(aim_s[n] * fd);
            acc += 2.0f * (cdr_s[n] * wr - cdi_s[n] * wi);
        }
        ws[OFF_K + h * CHK + d] = acc;
    }
}

// ---------------------------------------------------------------------------
// Kernel A: u = gelu(W_lin @ x + b_lin)   (pointwise over l, mixes channels)
// ---------------------------------------------------------------------------
__global__ void k_ulin(const float* __restrict__ x, const float* __restrict__ W,
                       const float* __restrict__ bl, float* __restrict__ ws) {
    __shared__ float W_s[1024];
    __shared__ float b_s[32];
    int t = threadIdx.x;
    for (int i = t; i < 1024; i += 256) W_s[i] = W[i];
    if (t < 32) b_s[t] = bl[t];
    __syncthreads();
    int blk = blockIdx.x;
    int b = blk >> 7;
    int l = ((blk & 127) << 8) + t;
    const float* xp = x + b * Hc * Lc + l;
    float xv[32];
#pragma unroll
    for (int h = 0; h < 32; ++h) xv[h] = xp[h * Lc];
    float* up = ws + OFF_U + b * Hc * Lc + l;
#pragma unroll
    for (int g = 0; g < 32; ++g) {
        float acc = b_s[g];
#pragma unroll
        for (int h = 0; h < 32; ++h) acc = fmaf(W_s[g * 32 + h], xv[h], acc);
        up[g * Lc] = gelu_f(acc);
    }
}

// ---------------------------------------------------------------------------
// Kernel S1: per-chunk reduction P[c][n] = sum_{j<256} w^(255-j) u[c*256+j].
// Grid 8192: block = (bh, group of 4 chunks). Writes P into OFF_SIN with
// TRANSPOSED layout [c][bh][n][2] (k_scanS converts in-place to Sin).
// ---------------------------------------------------------------------------
__global__ void k_scanP(float* __restrict__ ws) {
    int g = blockIdx.x;
    int bh = g >> 5;
    int c0 = (g & 31) << 2;
    int h = bh & 31;
    int t = threadIdx.x;
    __shared__ float u_s[1024];
    __shared__ float lo_s[32 * 34];   // [n] stride 34
    __shared__ float hi_s[32 * 36];   // [n] stride 36
    __shared__ float p16_s[64 * 66];  // [(cc*16+qq)] stride 66
    {
        float4 v = *(const float4*)(ws + OFF_U + bh * Lc + (c0 << 8) + 4 * t);
        *(float4*)(u_s + 4 * t) = v;
    }
    for (int id = t; id < 512; id += 256) {
        int n = id >> 4, r = id & 15;
        lo_s[n * 34 + 2 * r] = ws[OFF_LO + ((h * 32 + n) * 16 + r) * 2];
        lo_s[n * 34 + 2 * r + 1] = ws[OFF_LO + ((h * 32 + n) * 16 + r) * 2 + 1];
    }
    for (int id = t; id < 544; id += 256) {
        int n = id / 17, q = id - n * 17;
        hi_s[n * 36 + 2 * q] = ws[OFF_HI + ((h * 32 + n) * 17 + q) * 2];
        hi_s[n * 36 + 2 * q + 1] = ws[OFF_HI + ((h * 32 + n) * 17 + q) * 2 + 1];
    }
    __syncthreads();
    int n = t & 31;
    // register-cache lo row for this thread's n
    float lor[16], loi[16];
#pragma unroll
    for (int r = 0; r < 16; ++r) {
        lor[r] = lo_s[n * 34 + 2 * r];
        loi[r] = lo_s[n * 34 + 2 * r + 1];
    }
#pragma unroll
    for (int i = 0; i < 8; ++i) {
        int x = (t >> 5) + (i << 3);  // x = cc*16+qq, 0..63
        const float* ub = u_s + (x << 4);
        float pr = 0.f, pi = 0.f;
#pragma unroll
        for (int k = 0; k < 4; ++k) {
            float4 uq = *(const float4*)(ub + (k << 2));
            pr = fmaf(lor[15 - 4 * k], uq.x, pr); pi = fmaf(loi[15 - 4 * k], uq.x, pi);
            pr = fmaf(lor[14 - 4 * k], uq.y, pr); pi = fmaf(loi[14 - 4 * k], uq.y, pi);
            pr = fmaf(lor[13 - 4 * k], uq.z, pr); pi = fmaf(loi[13 - 4 * k], uq.z, pi);
            pr = fmaf(lor[12 - 4 * k], uq.w, pr); pi = fmaf(loi[12 - 4 * k], uq.w, pi);
        }
        p16_s[x * 66 + 2 * n] = pr;
        p16_s[x * 66 + 2 * n + 1] = pi;
    }
    __syncthreads();
    if (t < 128) {
        int cc = t >> 5, nn = t & 31;
        float Pr = 0.f, Pi = 0.f;
#pragma unroll
        for (int qq = 0; qq < 16; ++qq) {
            float hr = hi_s[nn * 36 + 2 * (15 - qq)];
            float hx = hi_s[nn * 36 + 2 * (15 - qq) + 1];
            float pr = p16_s[(cc * 16 + qq) * 66 + 2 * nn];
            float px = p16_s[(cc * 16 + qq) * 66 + 2 * nn + 1];
            Pr += hr * pr - hx * px;
            Pi += hr * px + hx * pr;
        }
        int off = OFF_SIN + ((c0 + cc) * 256 + bh) * 64 + 2 * nn;
        ws[off] = Pr;
        ws[off + 1] = Pi;
    }
}

// ---------------------------------------------------------------------------
// Kernel S2: sequential chunk-state scan, in place: P[c] -> Sin[c].
// 8192 independent (bh,n) scans; Sin[c] = state entering chunk c.
// Layout [c][bh][n][2] -> lane-consecutive 8B slots = coalesced per step.
// ---------------------------------------------------------------------------
__global__ void k_scanS(float* __restrict__ ws) {
    int tid = blockIdx.x * 256 + threadIdx.x;  // 0..8191 = bh*32+n
    int bh = tid >> 5;
    int n = tid & 31;
    int h = bh & 31;
    float wcr = ws[OFF_HI + ((h * 32 + n) * 17 + 16) * 2];
    float wci = ws[OFF_HI + ((h * 32 + n) * 17 + 16) * 2 + 1];
    float Sr = 0.f, Si = 0.f;
    float* base = ws + OFF_SIN + tid * 2;
    for (int c = 0; c < NCH; ++c) {
        float Pr = base[c * 16384];
        float Pi = base[c * 16384 + 1];
        base[c * 16384] = Sr;
        base[c * 16384 + 1] = Si;
        float nSr = wcr * Sr - wci * Si + Pr;
        Si = wcr * Si + wci * Sr + Pi;
        Sr = nSr;
    }
}

// ---------------------------------------------------------------------------
// Kernel E v3: per-chunk SSM output: y = local_conv(K,u) + carry(Sin) + D*u
// Block = (bh, 4 chunks); wave cc handles one chunk; lane l owns m=4l..4l+3.
// float4 shared arrays force ds_read_b128 (conflict-free contiguous pattern).
// Carry uses precomputed G = Cd*Sin (wave-uniform broadcast reads).
// ---------------------------------------------------------------------------
__global__ void k_ssm(const float* __restrict__ Dp, float* __restrict__ ws,
                      float* __restrict__ ybuf) {
    int g = blockIdx.x;
    int bh = g >> 5;
    int c0 = (g & 31) << 2;
    int h = bh & 31;
    int t = threadIdx.x;
    __shared__ float4 u4v[4][66];     // [cc][0]=zero pad, [1..64]=u quads
    __shared__ float4 K4[64];
    __shared__ float loT_s[16 * 66];  // [r][2n] r-major
    __shared__ float hiT_s[16 * 66];  // [q][2n] q-major
    __shared__ float g_s[256];        // [cc][n][2]: G = Cd*Sin
    {
        const float* up = ws + OFF_U + bh * Lc + (c0 << 8);
        float4 v = *(const float4*)(up + 4 * t);
        u4v[t >> 6][1 + (t & 63)] = v;
        if (t < 4) u4v[t][0] = float4{0.f, 0.f, 0.f, 0.f};
    }
    if (t < 64) K4[t] = *(const float4*)(ws + OFF_K + (h << 8) + 4 * t);
    for (int id = t; id < 512; id += 256) {
        int n = id >> 4, r = id & 15;
        loT_s[r * 66 + 2 * n] = ws[OFF_LO + ((h * 32 + n) * 16 + r) * 2];
        loT_s[r * 66 + 2 * n + 1] = ws[OFF_LO + ((h * 32 + n) * 16 + r) * 2 + 1];
        hiT_s[r * 66 + 2 * n] = ws[OFF_HI + ((h * 32 + n) * 17 + r) * 2];
        hiT_s[r * 66 + 2 * n + 1] = ws[OFF_HI + ((h * 32 + n) * 17 + r) * 2 + 1];
    }
    if (t < 128) {
        int cc = t >> 5, nn = t & 31;
        int off = OFF_SIN + ((c0 + cc) * 256 + bh) * 64 + 2 * nn;
        float sr = ws[off], si = ws[off + 1];
        float cdr = ws[OFF_CD + (h * 32 + nn) * 2];
        float cdi = ws[OFF_CD + (h * 32 + nn) * 2 + 1];
        g_s[cc * 64 + 2 * nn] = cdr * sr - cdi * si;
        g_s[cc * 64 + 2 * nn + 1] = cdr * si + cdi * sr;
    }
    __syncthreads();
    int cc = t >> 6, l = t & 63;
    int m0 = l << 2;
    // ---- in-chunk causal conv, 4 outputs, rolling b128 window ----
    float a0 = 0.f, a1 = 0.f, a2 = 0.f, a3 = 0.f;
    float4 Bq = u4v[cc][1 + l];
#pragma unroll 2
    for (int k = 0; k <= l; ++k) {
        float4 Kq = K4[k];
        float4 Aq = u4v[cc][l - k];
        // window W[0..7] = {Aq.x..w, Bq.x..w};  y[m0+j] += K[4k+kk]*W[4+j-kk]
        a0 = fmaf(Kq.x, Bq.x, a0); a0 = fmaf(Kq.y, Aq.w, a0); a0 = fmaf(Kq.z, Aq.z, a0); a0 = fmaf(Kq.w, Aq.y, a0);
        a1 = fmaf(Kq.x, Bq.y, a1); a1 = fmaf(Kq.y, Bq.x, a1); a1 = fmaf(Kq.z, Aq.w, a1); a1 = fmaf(Kq.w, Aq.z, a1);
        a2 = fmaf(Kq.x, Bq.z, a2); a2 = fmaf(Kq.y, Bq.y, a2); a2 = fmaf(Kq.z, Bq.x, a2); a2 = fmaf(Kq.w, Aq.w, a2);
        a3 = fmaf(Kq.x, Bq.w, a3); a3 = fmaf(Kq.y, Bq.z, a3); a3 = fmaf(Kq.z, Bq.y, a3); a3 = fmaf(Kq.w, Bq.x, a3);
        Bq = Aq;
    }
    // ---- carry: car_j = Re sum_n G_n w^(m0+1+j),  w^(m0+1) = hi[q1]*lo[r1] ----
    int q1 = l >> 2;           // (m0+1)>>4
    int r1 = (m0 + 1) & 15;
    const float* hp = hiT_s + q1 * 66;
    const float* lp = loT_s + r1 * 66;
    const float* w1p = loT_s + 1 * 66;
    const float* gg = g_s + (cc << 6);
    float c0r = 0.f, c1r = 0.f, c2r = 0.f, c3r = 0.f;
#pragma unroll
    for (int n = 0; n < 32; ++n) {
        float hr = hp[2 * n], hx = hp[2 * n + 1];
        float lr = lp[2 * n], li = lp[2 * n + 1];
        float wqr = hr * lr - hx * li;
        float wqi = hr * li + hx * lr;           // w^(m0+1)
        float gr = gg[2 * n], gi = gg[2 * n + 1];
        float zr = gr * wqr - gi * wqi;
        float zi = gr * wqi + gi * wqr;          // G*w^(m0+1)
        c0r += zr;
        float w1r = w1p[2 * n], w1i = w1p[2 * n + 1];
        float t1r = zr * w1r - zi * w1i, t1i = zr * w1i + zi * w1r;
        c1r += t1r;
        float t2r = t1r * w1r - t1i * w1i, t2i = t1r * w1i + t1i * w1r;
        c2r += t2r;
        float t3r = t2r * w1r - t2i * w1i;
        c3r += t3r;
    }
    // ---- combine + write ----
    float4 uq = u4v[cc][1 + l];
    float Dh = Dp[h];
    float4 o;
    o.x = a0 + 2.f * c0r + Dh * uq.x;
    o.y = a1 + 2.f * c1r + Dh * uq.y;
    o.z = a2 + 2.f * c2r + Dh * uq.z;
    o.w = a3 + 2.f * c3r + Dh * uq.w;
    *(float4*)(ybuf + bh * Lc + ((c0 + cc) << 8) + m0) = o;
}

// ---------------------------------------------------------------------------
// Kernel F: z = W_out @ y + b_out (64 ch); yg = z1 * sigmoid(z2) -> into u buf
// ---------------------------------------------------------------------------
__global__ void k_glu(const float* __restrict__ Wout, const float* __restrict__ bout,
                      const float* __restrict__ ybuf, float* __restrict__ ws) {
    __shared__ float W_s[2048];
    __shared__ float b_s[64];
    int t = threadIdx.x;
    for (int i = t; i < 2048; i += 256) W_s[i] = Wout[i];
    if (t < 64) b_s[t] = bout[t];
    __syncthreads();
    int blk = blockIdx.x;
    int b = blk >> 7;
    int l = ((blk & 127) << 8) + t;
    const float* yp = ybuf + b * Hc * Lc + l;
    float yv[32];
#pragma unroll
    for (int h = 0; h < 32; ++h) yv[h] = yp[h * Lc];
    float* op = ws + OFF_U + b * Hc * Lc + l;  // yg overwrites u (dead)
#pragma unroll
    for (int g = 0; g < 32; ++g) {
        float a1 = b_s[g], a2 = b_s[g + 32];
#pragma unroll
        for (int h = 0; h < 32; ++h) {
            a1 = fmaf(W_s[g * 32 + h], yv[h], a1);
            a2 = fmaf(W_s[(g + 32) * 32 + h], yv[h], a2);
        }
        float sg = 1.f / (1.f + expf(-a2));
        op[g * Lc] = a1 * sg;
    }
}

// ---------------------------------------------------------------------------
// Kernel R: per-channel partial sums for BatchNorm stats
// ---------------------------------------------------------------------------
__global__ void k_stats(float* __restrict__ ws) {
    int blk = blockIdx.x;  // g*8 + s
    int g = blk >> 3, s = blk & 7;
    int t = threadIdx.x;
    float s1 = 0.f, s2 = 0.f;
    const float* yg = ws + OFF_U;
    for (int b = 0; b < 8; ++b) {
        const float* p = yg + b * Hc * Lc + g * Lc + s * 4096 + t * 16;
#pragma unroll
        for (int j = 0; j < 4; ++j) {
            float4 v = *(const float4*)(p + j * 4);
            s1 += v.x + v.y + v.z + v.w;
            s2 += v.x * v.x + v.y * v.y + v.z * v.z + v.w * v.w;
        }
    }
    __shared__ float r1[256], r2[256];
    r1[t] = s1;
    r2[t] = s2;
    __syncthreads();
    for (int off = 128; off > 0; off >>= 1) {
        if (t < off) {
            r1[t] += r1[t + off];
            r2[t] += r2[t + off];
        }
        __syncthreads();
    }
    if (t == 0) {
        ws[OFF_SUMP + blk] = r1[0];
        ws[OFF_SQP + blk] = r2[0];
    }
}

// ---------------------------------------------------------------------------
// Kernel G: finalize BN stats + FiLM projection gb = cond @ film_W^T + film_b
// ---------------------------------------------------------------------------
__global__ void k_finalize(const float* __restrict__ cond, const float* __restrict__ filmW,
                           const float* __restrict__ filmb, float* __restrict__ ws) {
    int t = threadIdx.x;
    if (t < 32) {
        float su = 0.f, sq = 0.f;
        for (int s = 0; s < 8; ++s) {
            su += ws[OFF_SUMP + t * 8 + s];
            sq += ws[OFF_SQP + t * 8 + s];
        }
        float inv_cnt = 1.0f / (float)(Bsz * Lc);
        float mean = su * inv_cnt;
        float var = sq * inv_cnt - mean * mean;
        ws[OFF_MEAN + t] = mean;
        ws[OFF_INV + t] = rsqrtf(var + 1e-5f);
    }
    for (int id = t; id < 512; id += 256) {
        int b = id >> 6, j = id & 63;
        float acc = filmb[j];
        for (int k = 0; k < 128; ++k) acc = fmaf(cond[b * 128 + k], filmW[j * 128 + k], acc);
        ws[OFF_GB + id] = acc;
    }
}

// ---------------------------------------------------------------------------
// Kernel H: out = gelu(gamma*(yg-mean)*inv + beta) + res_w * x
// ---------------------------------------------------------------------------
__global__ void k_final(const float* __restrict__ x, const float* __restrict__ resw,
                        const float* __restrict__ ws, float* __restrict__ out) {
    int i = blockIdx.x * 256 + threadIdx.x;  // over 2097152 float4 groups
    int l4 = i & 8191;
    int hl = i >> 13;
    int h = hl & 31;
    int b = hl >> 5;
    float mean = ws[OFF_MEAN + h], inv = ws[OFF_INV + h];
    float gam = ws[OFF_GB + b * 64 + h], bet = ws[OFF_GB + b * 64 + 32 + h];
    float rw = resw[h];
    int base = hl * Lc + l4 * 4;
    float4 yv = *(const float4*)(ws + OFF_U + base);
    float4 xv = *(const float4*)(x + base);
    float4 o;
    o.x = gelu_f(fmaf(gam, (yv.x - mean) * inv, bet)) + rw * xv.x;
    o.y = gelu_f(fmaf(gam, (yv.y - mean) * inv, bet)) + rw * xv.y;
    o.z = gelu_f(fmaf(gam, (yv.z - mean) * inv, bet)) + rw * xv.z;
    o.w = gelu_f(fmaf(gam, (yv.w - mean) * inv, bet)) + rw * xv.w;
    *(float4*)(out + base) = o;
}

// ---------------------------------------------------------------------------
extern "C" void kernel_launch(void* const* d_in, const int* in_sizes, int n_in,
                              void* d_out, int out_size, void* d_ws, size_t ws_size,
                              hipStream_t stream) {
    const float* x = (const float*)d_in[0];
    const float* cond = (const float*)d_in[1];
    const float* W_lin = (const float*)d_in[2];
    const float* b_lin = (const float*)d_in[3];
    const float* log_dt = (const float*)d_in[4];
    const float* A_re = (const float*)d_in[5];
    const float* A_im = (const float*)d_in[6];
    const float* C_re = (const float*)d_in[7];
    const float* C_im = (const float*)d_in[8];
    const float* Dp = (const float*)d_in[9];
    const float* W_out = (const float*)d_in[10];
    const float* b_out = (const float*)d_in[11];
    const float* film_W = (const float*)d_in[12];
    const float* film_b = (const float*)d_in[13];
    const float* res_w = (const float*)d_in[14];
    float* ws = (float*)d_ws;
    float* out = (float*)d_out;

    hipLaunchKernelGGL(k_tables, dim3(32), dim3(256), 0, stream, log_dt, A_re, A_im, C_re, C_im, ws);
    hipLaunchKernelGGL(k_ulin, dim3(1024), dim3(256), 0, stream, x, W_lin, b_lin, ws);
    hipLaunchKernelGGL(k_scanP, dim3(8192), dim3(256), 0, stream, ws);
    hipLaunchKernelGGL(k_scanS, dim3(32), dim3(256), 0, stream, ws);
    hipLaunchKernelGGL(k_ssm, dim3(8192), dim3(256), 0, stream, Dp, ws, out);
    hipLaunchKernelGGL(k_glu, dim3(1024), dim3(256), 0, stream, W_out, b_out, out, ws);
    hipLaunchKernelGGL(k_stats, dim3(256), dim3(256), 0, stream, ws);
    hipLaunchKernelGGL(k_finalize, dim3(1), dim3(256), 0, stream, cond, film_W, film_b, ws);
    hipLaunchKernelGGL(k_final, dim3(8192), dim3(256), 0, stream, x, res_w, ws, out);
}